// Round 8
// baseline (167.387 us; speedup 1.0000x reference)
//
#include <hip/hip_runtime.h>

typedef unsigned short u16;
typedef __attribute__((ext_vector_type(8))) short bf16x8;
typedef __attribute__((ext_vector_type(4))) short bf16x4;
typedef __attribute__((ext_vector_type(4))) float f32x4;

#define NB 2
#define SEQ 2048
#define HID 1024
#define NHEAD 16
#define HD 64
#define MROWS (NB * SEQ) /* 4096 */

__device__ __forceinline__ u16 f2bf(float f) {
  union { float f; unsigned u; } x; x.f = f;
  unsigned r = x.u + 0x7fffu + ((x.u >> 16) & 1u);
  return (u16)(r >> 16);
}
__device__ __forceinline__ u16 f2bf_trunc(float f) {
  union { float f; unsigned u; } x; x.f = f;
  return (u16)(x.u >> 16);
}

#define GLOAD_LDS16(g, l)                                                   \
  __builtin_amdgcn_global_load_lds(                                         \
      (const __attribute__((address_space(1))) void*)(g),                   \
      (__attribute__((address_space(3))) void*)(l), 16, 0, 0)

// single-tensor f32 -> bf16 (fallback path)
__global__ __launch_bounds__(256)
void conv_f32_bf16(const float* __restrict__ src, u16* __restrict__ dst, int nvec)
{
  const int i = blockIdx.x * 256 + threadIdx.x;
  if (i >= nvec) return;
  const float* s = src + (size_t)i * 8;
  f32x4 a = *(const f32x4*)s;
  f32x4 b = *(const f32x4*)(s + 4);
  bf16x8 o;
#pragma unroll
  for (int j = 0; j < 4; ++j) { o[j] = (short)f2bf(a[j]); o[4 + j] = (short)f2bf(b[j]); }
  *(bf16x8*)(dst + (size_t)i * 8) = o;
}

// all-tensor f32 -> bf16: q,k,v (4M elems each) + Wq,Wk,Wv -> Wcat + Wp -> Wpb
__global__ __launch_bounds__(256)
void conv_all(const float* __restrict__ q, const float* __restrict__ k,
              const float* __restrict__ v, const float* __restrict__ wq,
              const float* __restrict__ wk, const float* __restrict__ wv,
              const float* __restrict__ wp, u16* __restrict__ qb,
              u16* __restrict__ kb, u16* __restrict__ vb,
              u16* __restrict__ wcat, u16* __restrict__ wpb)
{
  const int i = blockIdx.x * 256 + threadIdx.x;  // vec8 index, < 2097152
  const float* s; u16* d;
  if (i < 1572864) {
    const int seg = i / 524288;          // 0=q 1=k 2=v
    const int off = i - seg * 524288;
    s = (seg == 0 ? q : seg == 1 ? k : v) + (size_t)off * 8;
    d = (seg == 0 ? qb : seg == 1 ? kb : vb) + (size_t)off * 8;
  } else {
    const int j = i - 1572864;
    const int seg = j / 131072;          // 0=Wq 1=Wk 2=Wv 3=Wp
    const int off = j - seg * 131072;
    s = (seg == 0 ? wq : seg == 1 ? wk : seg == 2 ? wv : wp) + (size_t)off * 8;
    d = (seg < 3 ? wcat + (size_t)seg * 1048576 : wpb) + (size_t)off * 8;
  }
  f32x4 a = *(const f32x4*)s;
  f32x4 b = *(const f32x4*)(s + 4);
  bf16x8 o;
#pragma unroll
  for (int j = 0; j < 4; ++j) { o[j] = (short)f2bf(a[j]); o[4 + j] = (short)f2bf(b[j]); }
  *(bf16x8*)d = o;
}

// 128x128x32 m97-structure GEMM.  C = (A @ W.T + bias) * scale.
// MODE 0 (QKV): column group g = n0>>10 selects A/bias/epilogue:
//   wm==0 -> Qh split-head bf16 (scaled), wm==1 -> Kh split-head,
//   wm==2 -> Vt transposed [b][h][d][n].
// MODE 1: f32 row-major Op.
// wparam: -1 = derive wm from g (fused); else fixed wm (separate launches).
template<int MODE>
__global__ __launch_bounds__(256)
void gemm128(const u16* __restrict__ A0, const u16* __restrict__ A1,
             const u16* __restrict__ A2, const u16* __restrict__ W,
             const float* __restrict__ b0, const float* __restrict__ b1,
             const float* __restrict__ b2,
             u16* __restrict__ Qh, u16* __restrict__ Kh, u16* __restrict__ Vt,
             float* __restrict__ Op, int wparam, float qscale)
{
  __shared__ u16 As[128 * 32];   // 8 KB, linear
  __shared__ u16 Bs[128 * 32];   // 8 KB
  const int n0 = blockIdx.x * 128, m0 = blockIdx.y * 128;
  const int g = n0 >> 10;
  const int wm = wparam < 0 ? g : wparam;
  const u16* A = (g == 0) ? A0 : (g == 1) ? A1 : A2;
  const float* bias = (wm == 0) ? b0 : (wm == 1) ? b1 : b2;
  const float scale = (MODE == 0 && wm == 0) ? qscale : 1.f;
  const int t = threadIdx.x, lane = t & 63, w = t >> 6;
  const int grp = lane >> 4, lr = lane & 15;
  const int wr = (w >> 1) * 64, wc = (w & 1) * 64;

  f32x4 acc[4][4];
#pragma unroll
  for (int i = 0; i < 4; ++i)
#pragma unroll
    for (int j = 0; j < 4; ++j) acc[i][j] = (f32x4){0.f, 0.f, 0.f, 0.f};

  // staging: wave w covers rows [w*32, w*32+32); lane l -> row +l/4, col (l&3)*8
  const int sr = lane >> 2, sc = (lane & 3) * 8;
  const u16* ag = A + (size_t)(m0 + w * 32 + sr) * HID + sc;
  const u16* wg = W + (size_t)(n0 + w * 32 + sr) * HID + sc;
  u16* al = As + (w * 32) * 32;
  u16* bl = Bs + (w * 32) * 32;

  for (int k0 = 0; k0 < HID; k0 += 32) {
    GLOAD_LDS16(ag + k0, al);
    GLOAD_LDS16(ag + (size_t)16 * HID + k0, al + 16 * 32);
    GLOAD_LDS16(wg + k0, bl);
    GLOAD_LDS16(wg + (size_t)16 * HID + k0, bl + 16 * 32);
    __syncthreads();
    bf16x8 af[4], bf[4];
#pragma unroll
    for (int mi = 0; mi < 4; ++mi)
      af[mi] = *(const bf16x8*)&As[(wr + mi * 16 + lr) * 32 + grp * 8];
#pragma unroll
    for (int ni = 0; ni < 4; ++ni)
      bf[ni] = *(const bf16x8*)&Bs[(wc + ni * 16 + lr) * 32 + grp * 8];
    __builtin_amdgcn_s_setprio(1);
#pragma unroll
    for (int mi = 0; mi < 4; ++mi)
#pragma unroll
      for (int ni = 0; ni < 4; ++ni)
        acc[mi][ni] = __builtin_amdgcn_mfma_f32_16x16x32_bf16(
            af[mi], bf[ni], acc[mi][ni], 0, 0, 0);
    __builtin_amdgcn_s_setprio(0);
    __syncthreads();
  }

#pragma unroll
  for (int mi = 0; mi < 4; ++mi) {
#pragma unroll
    for (int ni = 0; ni < 4; ++ni) {
      const int n = n0 + wc + ni * 16 + lr;
      const int nl = n & (HID - 1);
      const float bval = bias[nl];
      const int mb = m0 + wr + mi * 16 + grp * 4;
      if (MODE == 1) {
#pragma unroll
        for (int r = 0; r < 4; ++r)
          Op[(size_t)(mb + r) * HID + n] = acc[mi][ni][r] + bval;
      } else {
        const int h = nl >> 6, d = nl & (HD - 1);
        if (wm == 2) {  // V transposed: vector over r (m-contiguous)
          const int b = mb >> 11, nn = mb & (SEQ - 1);
          bf16x4 pk;
#pragma unroll
          for (int r = 0; r < 4; ++r)
            pk[r] = (short)f2bf(acc[mi][ni][r] + bval);
          *(bf16x4*)&Vt[((size_t)(b * NHEAD + h) * HD + d) * SEQ + nn] = pk;
        } else {
          u16* O = (wm == 0) ? Qh : Kh;
#pragma unroll
          for (int r = 0; r < 4; ++r) {
            const int m = mb + r;
            const int b = m >> 11, nn = m & (SEQ - 1);
            O[((size_t)(b * NHEAD + h) * SEQ + nn) * HD + d] =
                f2bf((acc[mi][ni][r] + bval) * scale);
          }
        }
      }
    }
  }
}

// Causal flash attention, PAIRED q-tiles (qtA, qtB=15-qtA) of one bh.
// MERGED streams: K-frags and V-frags are q-independent -> read once per
// iteration, feed both streams' MFMAs. 3-buffer LDS, 2-ahead prefetch,
// counted vmcnt(2) (T4). QBLK=128 (8 waves x 16 q/stream), KVBLK=64.
// Q pre-scaled by 0.125*log2(e). Q,K: [bh][n][64]; Vt: [bh][64][n]; bf16.
// O: [b][n][HID] bf16. chunk ^= (row&7) XOR swizzle, pre-swizzled source.
__global__ __launch_bounds__(512)
void attn_fwd(const u16* __restrict__ Q, const u16* __restrict__ K,
              const u16* __restrict__ Vt, u16* __restrict__ O)
{
  __shared__ u16 KB[3][4096];   // [buf][64 kv][64 d], 8 KB each
  __shared__ u16 VB[3][4096];   // [buf][64 d][64 kv], 8 KB each
  const int bh = blockIdx.y;
  const int t = threadIdx.x;
  const int w = t >> 6, lane = t & 63;
  const int grp = lane >> 4, lr = lane & 15;
  const int qtA = blockIdx.x;          // 0..7  (light tile)
  const int qtB = 15 - qtA;            // 8..15 (heavy tile)
  const int q0A = qtA * 128 + w * 16;
  const int q0B = qtB * 128 + w * 16;
  const int ntB = 2 * qtB + 2;         // staged kv tiles (covers A too)
  const size_t base = (size_t)bh * SEQ * HD;
  const float NEGINF = -__builtin_inff();

  // staging: wave w covers tile rows [w*8, w*8+8); chunk pre-swizzled
  const int srow = lane >> 3;
  const int scol = (lane & 7) ^ srow;
  const u16* kg = K + base + (size_t)(w * 8 + srow) * HD + scol * 8;
  const u16* vg = Vt + base + (size_t)(w * 8 + srow) * SEQ + scol * 8;

  const bf16x8 aqA0 = *(const bf16x8*)&Q[base + (size_t)(q0A + lr) * HD + grp * 8];
  const bf16x8 aqA1 = *(const bf16x8*)&Q[base + (size_t)(q0A + lr) * HD + grp * 8 + 32];
  const bf16x8 aqB0 = *(const bf16x8*)&Q[base + (size_t)(q0B + lr) * HD + grp * 8];
  const bf16x8 aqB1 = *(const bf16x8*)&Q[base + (size_t)(q0B + lr) * HD + grp * 8 + 32];

  float mA = NEGINF, lA = 0.f, mB = NEGINF, lB = 0.f;
  f32x4 oA[4], oB[4];
#pragma unroll
  for (int c = 0; c < 4; ++c) {
    oA[c] = (f32x4){0.f, 0.f, 0.f, 0.f};
    oB[c] = (f32x4){0.f, 0.f, 0.f, 0.f};
  }

  const int idqA = q0A >> 6;   // this wave's diagonal tile in stream A
  const int idqB = q0B >> 6;
  const int sw = lr & 7;

#define STAGE(bi, j0)                                              \
  {                                                                \
    GLOAD_LDS16(kg + (size_t)(j0) * HD, &KB[bi][w * 512]);         \
    GLOAD_LDS16(vg + (j0), &VB[bi][w * 512]);                      \
  }

// mask + online softmax + pack + PV for one stream (uses shared bv)
#define SMAXPV(SV, OACC, MI, LI, IDQ, Q0)                                     \
  do {                                                                        \
    if (it == (IDQ)) {                                                        \
      const int j0 = it << 6, qg = (Q0) + lr;                                 \
      _Pragma("unroll")                                                       \
      for (int st = 0; st < 4; ++st)                                          \
        _Pragma("unroll")                                                     \
        for (int r = 0; r < 4; ++r)                                           \
          if (j0 + st * 16 + grp * 4 + r > qg) (SV)[st][r] = NEGINF;          \
    }                                                                         \
    float tm = NEGINF;                                                        \
    _Pragma("unroll")                                                         \
    for (int st = 0; st < 4; ++st)                                            \
      tm = fmaxf(tm, fmaxf(fmaxf((SV)[st][0], (SV)[st][1]),                   \
                           fmaxf((SV)[st][2], (SV)[st][3])));                 \
    tm = fmaxf(tm, __shfl_xor(tm, 16));                                       \
    tm = fmaxf(tm, __shfl_xor(tm, 32));                                       \
    if (!__all(tm <= (MI) + 8.f)) {                                           \
      const float m_new = fmaxf((MI), tm);                                    \
      const float alpha = exp2f((MI)-m_new);                                  \
      (LI) *= alpha;                                                          \
      float af4[4];                                                           \
      _Pragma("unroll")                                                       \
      for (int r = 0; r < 4; ++r)                                             \
        af4[r] = __shfl(alpha, (lane & 48) + grp * 4 + r);                    \
      _Pragma("unroll")                                                       \
      for (int c = 0; c < 4; ++c)                                             \
        _Pragma("unroll")                                                     \
        for (int r = 0; r < 4; ++r) (OACC)[c][r] *= af4[r];                   \
      (MI) = m_new;                                                           \
    }                                                                         \
    float rs = 0.f;                                                           \
    _Pragma("unroll")                                                         \
    for (int st = 0; st < 4; ++st)                                            \
      _Pragma("unroll")                                                       \
      for (int r = 0; r < 4; ++r) {                                           \
        (SV)[st][r] = exp2f((SV)[st][r] - (MI));                              \
        rs += (SV)[st][r];                                                    \
      }                                                                       \
    rs += __shfl_xor(rs, 16);                                                 \
    rs += __shfl_xor(rs, 32);                                                 \
    (LI) += rs;                                                               \
    bf16x4 pa[4];                                                             \
    _Pragma("unroll")                                                         \
    for (int st = 0; st < 4; ++st)                                            \
      _Pragma("unroll")                                                       \
      for (int r = 0; r < 4; ++r) pa[st][r] = (short)f2bf_trunc((SV)[st][r]); \
    __builtin_amdgcn_s_setprio(1);                                            \
    _Pragma("unroll")                                                         \
    for (int st = 0; st < 4; ++st)                                            \
      _Pragma("unroll")                                                       \
      for (int c = 0; c < 4; ++c)                                             \
        (OACC)[c] = __builtin_amdgcn_mfma_f32_16x16x16bf16_1k(                \
            pa[st], bv[st][c], (OACC)[c], 0, 0, 0);                           \
    __builtin_amdgcn_s_setprio(0);                                            \
  } while (0)

  STAGE(0, 0);
  STAGE(1, 64);

  for (int it = 0; it < ntB; ++it) {
    const int bi = it % 3;
    // own 2 loads for tile it are the oldest; tile it+1's may stay in flight
    if (it + 1 < ntB) asm volatile("s_waitcnt vmcnt(2)" ::: "memory");
    else              asm volatile("s_waitcnt vmcnt(0)" ::: "memory");
    __builtin_amdgcn_s_barrier();
    __builtin_amdgcn_sched_barrier(0);
    asm volatile("" ::: "memory");
    if (it + 2 < ntB) STAGE((it + 2) % 3, (it + 2) << 6);

    if (it <= idqB) {
      const bool doA = (it <= idqA);
      // ---- QK^T both streams off shared K-frags ----
      f32x4 svB[4], svA[4];
      __builtin_amdgcn_s_setprio(1);
#pragma unroll
      for (int st = 0; st < 4; ++st) {
        const int ro = (st * 16 + lr) * 64;
        bf16x8 k0 = *(const bf16x8*)&KB[bi][ro + ((grp ^ sw) * 8)];
        bf16x8 k1 = *(const bf16x8*)&KB[bi][ro + (((grp + 4) ^ sw) * 8)];
        f32x4 s = (f32x4){0.f, 0.f, 0.f, 0.f};
        s = __builtin_amdgcn_mfma_f32_16x16x32_bf16(k0, aqB0, s, 0, 0, 0);
        s = __builtin_amdgcn_mfma_f32_16x16x32_bf16(k1, aqB1, s, 0, 0, 0);
        svB[st] = s;
        if (doA) {
          f32x4 s2 = (f32x4){0.f, 0.f, 0.f, 0.f};
          s2 = __builtin_amdgcn_mfma_f32_16x16x32_bf16(k0, aqA0, s2, 0, 0, 0);
          s2 = __builtin_amdgcn_mfma_f32_16x16x32_bf16(k1, aqA1, s2, 0, 0, 0);
          svA[st] = s2;
        }
      }
      __builtin_amdgcn_s_setprio(0);
      // ---- shared V-frags (independent -> hide under softmax) ----
      bf16x4 bv[4][4];
#pragma unroll
      for (int st = 0; st < 4; ++st)
#pragma unroll
        for (int c = 0; c < 4; ++c)
          bv[st][c] = *(const bf16x4*)&VB[bi][(c * 16 + lr) * 64 +
                          (((st * 2 + (grp >> 1)) ^ sw) * 8) + (grp & 1) * 4];
      SMAXPV(svB, oB, mB, lB, idqB, q0B);
      if (doA) SMAXPV(svA, oA, mA, lA, idqA, q0A);
    }
  }
#undef STAGE
#undef SMAXPV

  const int b = bh >> 4, h = bh & (NHEAD - 1);
#pragma unroll
  for (int r = 0; r < 4; ++r) {
    const float liB = __shfl(lB, (lane & 48) + grp * 4 + r);
    const float invB = 1.f / liB;
    const int nB = q0B + grp * 4 + r;
#pragma unroll
    for (int c = 0; c < 4; ++c)
      O[(size_t)(b * SEQ + nB) * HID + h * HD + c * 16 + lr] =
          f2bf(oB[c][r] * invB);
    const float liA = __shfl(lA, (lane & 48) + grp * 4 + r);
    const float invA = 1.f / liA;
    const int nA = q0A + grp * 4 + r;
#pragma unroll
    for (int c = 0; c < 4; ++c)
      O[(size_t)(b * SEQ + nA) * HID + h * HD + c * 16 + lr] =
          f2bf(oA[c][r] * invA);
  }
}

extern "C" void kernel_launch(void* const* d_in, const int* in_sizes, int n_in,
                              void* d_out, int out_size, void* d_ws, size_t ws_size,
                              hipStream_t stream) {
  const float* q  = (const float*)d_in[0];
  const float* k  = (const float*)d_in[1];
  const float* v  = (const float*)d_in[2];
  /* d_in[3] = mask: tril by construction -> causal handled structurally */
  const float* Wq = (const float*)d_in[4];
  const float* bq = (const float*)d_in[5];
  const float* Wk = (const float*)d_in[6];
  const float* bk = (const float*)d_in[7];
  const float* Wv = (const float*)d_in[8];
  const float* bv = (const float*)d_in[9];
  const float* Wp = (const float*)d_in[10];
  const float* bp = (const float*)d_in[11];
  float* out = (float*)d_out;

  char* ws = (char*)d_ws;
  const float qscale = 0.125f * 1.4426950408889634f;  // 1/sqrt(64) * log2(e)
  const dim3 ablk(8, NB * NHEAD);                     // paired q-tiles

  if (ws_size >= (56u << 20)) {
    // fused path (56 MiB): qb kb vb | Wcat(3x) Wpb | Qh Kh Vt ; AO aliases qb
    u16* qb   = (u16*)(ws);
    u16* kb   = (u16*)(ws + ( 8u << 20));
    u16* vb   = (u16*)(ws + (16u << 20));
    u16* Wcat = (u16*)(ws + (24u << 20));
    u16* Wpb  = (u16*)(ws + (30u << 20));
    u16* Qh   = (u16*)(ws + (32u << 20));
    u16* Kh   = (u16*)(ws + (40u << 20));
    u16* Vt   = (u16*)(ws + (48u << 20));
    u16* AO   = qb;

    conv_all<<<8192, 256, 0, stream>>>(q, k, v, Wq, Wk, Wv, Wp,
                                       qb, kb, vb, Wcat, Wpb);
    gemm128<0><<<dim3(24, 32), 256, 0, stream>>>(
        qb, kb, vb, Wcat, bq, bk, bv, Qh, Kh, Vt, nullptr, -1, qscale);
    attn_fwd<<<ablk, 512, 0, stream>>>(Qh, Kh, Vt, AO);
    gemm128<1><<<dim3(8, 32), 256, 0, stream>>>(
        AO, AO, AO, Wpb, bp, bp, bp, nullptr, nullptr, nullptr, out, 0, 1.f);
  } else {
    // fallback (40 MiB): cb | Wqb Wkb Wvb Wpb | Qh Kh Vt ; AO aliases cb
    u16* cb  = (u16*)(ws);
    u16* Wqb = (u16*)(ws + ( 8u << 20));
    u16* Wkb = (u16*)(ws + (10u << 20));
    u16* Wvb = (u16*)(ws + (12u << 20));
    u16* Wpb = (u16*)(ws + (14u << 20));
    u16* Qh  = (u16*)(ws + (16u << 20));
    u16* Kh  = (u16*)(ws + (24u << 20));
    u16* Vt  = (u16*)(ws + (32u << 20));
    u16* AO  = cb;
    const int NV_A = MROWS * HID / 8, NV_W = HID * HID / 8;

    conv_f32_bf16<<<NV_W / 256, 256, 0, stream>>>(Wq, Wqb, NV_W);
    conv_f32_bf16<<<NV_W / 256, 256, 0, stream>>>(Wk, Wkb, NV_W);
    conv_f32_bf16<<<NV_W / 256, 256, 0, stream>>>(Wv, Wvb, NV_W);
    conv_f32_bf16<<<NV_W / 256, 256, 0, stream>>>(Wp, Wpb, NV_W);

    conv_f32_bf16<<<NV_A / 256, 256, 0, stream>>>(q, cb, NV_A);
    gemm128<0><<<dim3(8, 32), 256, 0, stream>>>(
        cb, cb, cb, Wqb, bq, bk, bv, Qh, Kh, Vt, nullptr, 0, qscale);
    conv_f32_bf16<<<NV_A / 256, 256, 0, stream>>>(k, cb, NV_A);
    gemm128<0><<<dim3(8, 32), 256, 0, stream>>>(
        cb, cb, cb, Wkb, bq, bk, bv, Qh, Kh, Vt, nullptr, 1, qscale);
    conv_f32_bf16<<<NV_A / 256, 256, 0, stream>>>(v, cb, NV_A);
    gemm128<0><<<dim3(8, 32), 256, 0, stream>>>(
        cb, cb, cb, Wvb, bq, bk, bv, Qh, Kh, Vt, nullptr, 2, qscale);

    attn_fwd<<<ablk, 512, 0, stream>>>(Qh, Kh, Vt, AO);
    gemm128<1><<<dim3(8, 32), 256, 0, stream>>>(
        AO, AO, AO, Wpb, bp, bp, bp, nullptr, nullptr, nullptr, out, 0, 1.f);
  }
}

// Round 9
// 164.066 us; speedup vs baseline: 1.0202x; 1.0202x over previous
//
#include <hip/hip_runtime.h>

typedef unsigned short u16;
typedef __attribute__((ext_vector_type(8))) short bf16x8;
typedef __attribute__((ext_vector_type(4))) short bf16x4;
typedef __attribute__((ext_vector_type(4))) float f32x4;

#define NB 2
#define SEQ 2048
#define HID 1024
#define NHEAD 16
#define HD 64
#define MROWS (NB * SEQ) /* 4096 */

__device__ __forceinline__ u16 f2bf(float f) {
  union { float f; unsigned u; } x; x.f = f;
  unsigned r = x.u + 0x7fffu + ((x.u >> 16) & 1u);
  return (u16)(r >> 16);
}
__device__ __forceinline__ u16 f2bf_trunc(float f) {
  union { float f; unsigned u; } x; x.f = f;
  return (u16)(x.u >> 16);
}

#define GLOAD_LDS16(g, l)                                                   \
  __builtin_amdgcn_global_load_lds(                                         \
      (const __attribute__((address_space(1))) void*)(g),                   \
      (__attribute__((address_space(3))) void*)(l), 16, 0, 0)

// weights-only f32 -> bf16: Wq,Wk,Wv -> Wcat ; Wp -> Wpb  (524288 vec8)
__global__ __launch_bounds__(256)
void conv_w(const float* __restrict__ wq, const float* __restrict__ wk,
            const float* __restrict__ wv, const float* __restrict__ wp,
            u16* __restrict__ wcat, u16* __restrict__ wpb)
{
  const int i = blockIdx.x * 256 + threadIdx.x;  // < 524288
  const int seg = i >> 17;                        // /131072: 0=Wq 1=Wk 2=Wv 3=Wp
  const int off = i & 131071;
  const float* s = (seg == 0 ? wq : seg == 1 ? wk : seg == 2 ? wv : wp) +
                   (size_t)off * 8;
  u16* d = (seg < 3 ? wcat + (size_t)seg * 1048576 : wpb) + (size_t)off * 8;
  f32x4 a = *(const f32x4*)s;
  f32x4 b = *(const f32x4*)(s + 4);
  bf16x8 o;
#pragma unroll
  for (int j = 0; j < 4; ++j) { o[j] = (short)f2bf(a[j]); o[4 + j] = (short)f2bf(b[j]); }
  *(bf16x8*)d = o;
}

// Fused QKV projection GEMM, 128x128x32. A = f32 (q/k/v selected by column
// group g), converted to bf16 in-register during staging (no separate conv
// pass). W = pre-converted bf16 Wcat via global_load_lds. 2-buffer LDS,
// ONE raw barrier per k-step, counted vmcnt: W prefetch issued post-barrier
// (full MFMA phase to land, vmcnt(4)); A regs drained with vmcnt(2) after
// MFMA. Epilogue: g==0 -> Qh split-head bf16 (x qscale), g==1 -> Kh,
// g==2 -> Vt transposed [b][h][d][n].
__global__ __launch_bounds__(256)
void gemm_qkv(const float* __restrict__ A0, const float* __restrict__ A1,
              const float* __restrict__ A2, const u16* __restrict__ Wcat,
              const float* __restrict__ b0, const float* __restrict__ b1,
              const float* __restrict__ b2,
              u16* __restrict__ Qh, u16* __restrict__ Kh, u16* __restrict__ Vt,
              float qscale)
{
  __shared__ u16 As[2][4096];   // [buf][128 rows][32 k] bf16, 8 KB each
  __shared__ u16 Bs[2][4096];
  const int n0 = blockIdx.x * 128, m0 = blockIdx.y * 128;
  const int g = n0 >> 10;
  const float* A = (g == 0) ? A0 : (g == 1) ? A1 : A2;
  const float* bias = (g == 0) ? b0 : (g == 1) ? b1 : b2;
  const int t = threadIdx.x, lane = t & 63, w = t >> 6;
  const int grp = lane >> 4, lr = lane & 15;
  const int wr = (w >> 1) * 64, wc = (w & 1) * 64;

  f32x4 acc[4][4];
#pragma unroll
  for (int i = 0; i < 4; ++i)
#pragma unroll
    for (int j = 0; j < 4; ++j) acc[i][j] = (f32x4){0.f, 0.f, 0.f, 0.f};

  // W staging (gload_lds): wave w rows [w*32, +32), lane scatter 16B linear
  const int sr = lane >> 2, sc = (lane & 3) * 8;
  const u16* wg = Wcat + (size_t)(n0 + w * 32 + sr) * HID + sc;
  // A staging (f32 regs): row w*32 + lane/2, col half (lane&1)*16  (64B/lane)
  const int arow = w * 32 + (lane >> 1);
  const float* ag = A + (size_t)(m0 + arow) * HID + (lane & 1) * 16;
  const int lbase = arow * 32 + (lane & 1) * 16;  // LDS elem offset (linear)

  f32x4 a4[4];
#define ALOAD(K0)                                                   \
  { const float* p = ag + (K0);                                     \
    a4[0] = *(const f32x4*)p;       a4[1] = *(const f32x4*)(p + 4); \
    a4[2] = *(const f32x4*)(p + 8); a4[3] = *(const f32x4*)(p + 12); }
#define ACONV(BI)                                                   \
  { bf16x8 o0, o1;                                                  \
    _Pragma("unroll")                                               \
    for (int j = 0; j < 4; ++j) {                                   \
      o0[j] = (short)f2bf(a4[0][j]); o0[4 + j] = (short)f2bf(a4[1][j]); \
      o1[j] = (short)f2bf(a4[2][j]); o1[4 + j] = (short)f2bf(a4[3][j]); \
    }                                                               \
    *(bf16x8*)&As[BI][lbase] = o0; *(bf16x8*)&As[BI][lbase + 8] = o1; }
#define WSTAGE(BI, K0)                                              \
  { GLOAD_LDS16(wg + (K0), &Bs[BI][(w * 32) * 32]);                 \
    GLOAD_LDS16(wg + (size_t)16 * HID + (K0), &Bs[BI][(w * 32 + 16) * 32]); }

  // prologue: stage tile 0, issue A{1}
  ALOAD(0);
  asm volatile("s_waitcnt vmcnt(0)" ::: "memory");
  ACONV(0);
  WSTAGE(0, 0);
  ALOAD(32);
  asm volatile("s_waitcnt lgkmcnt(0)" ::: "memory");

  for (int it = 0; it < 32; ++it) {
    const int cur = it & 1;
    asm volatile("s_waitcnt vmcnt(4)" ::: "memory");  // W{it} landed; A{it+1} flies
    __builtin_amdgcn_s_barrier();
    __builtin_amdgcn_sched_barrier(0);
    WSTAGE(cur ^ 1, (it + 1 < 32) ? (it + 1) * 32 : 0);  // full phase to land
    bf16x8 af[4], bf[4];
#pragma unroll
    for (int mi = 0; mi < 4; ++mi)
      af[mi] = *(const bf16x8*)&As[cur][(wr + mi * 16 + lr) * 32 + grp * 8];
#pragma unroll
    for (int ni = 0; ni < 4; ++ni)
      bf[ni] = *(const bf16x8*)&Bs[cur][(wc + ni * 16 + lr) * 32 + grp * 8];
    __builtin_amdgcn_s_setprio(1);
#pragma unroll
    for (int mi = 0; mi < 4; ++mi)
#pragma unroll
      for (int ni = 0; ni < 4; ++ni)
        acc[mi][ni] = __builtin_amdgcn_mfma_f32_16x16x32_bf16(
            af[mi], bf[ni], acc[mi][ni], 0, 0, 0);
    __builtin_amdgcn_s_setprio(0);
    asm volatile("s_waitcnt vmcnt(2)" ::: "memory");  // A{it+1} regs ready
    ACONV(cur ^ 1);
    ALOAD((it + 2 < 32) ? (it + 2) * 32 : 0);
    asm volatile("s_waitcnt lgkmcnt(0)" ::: "memory");  // ds_writes visible
  }
  asm volatile("s_waitcnt vmcnt(0) lgkmcnt(0)" ::: "memory");
#undef ALOAD
#undef ACONV
#undef WSTAGE

  const float scale = (g == 0) ? qscale : 1.f;
#pragma unroll
  for (int mi = 0; mi < 4; ++mi) {
#pragma unroll
    for (int ni = 0; ni < 4; ++ni) {
      const int nl = (n0 & (HID - 1)) + wc + ni * 16 + lr;
      const float bval = bias[nl];
      const int mb = m0 + wr + mi * 16 + grp * 4;
      const int h = nl >> 6, d = nl & (HD - 1);
      if (g == 2) {  // V transposed: vector over r (m-contiguous)
        const int b = mb >> 11, nn = mb & (SEQ - 1);
        bf16x4 pk;
#pragma unroll
        for (int r = 0; r < 4; ++r)
          pk[r] = (short)f2bf(acc[mi][ni][r] + bval);
        *(bf16x4*)&Vt[((size_t)(b * NHEAD + h) * HD + d) * SEQ + nn] = pk;
      } else {
        u16* O = (g == 0) ? Qh : Kh;
#pragma unroll
        for (int r = 0; r < 4; ++r) {
          const int m = mb + r;
          const int b = m >> 11, nn = m & (SEQ - 1);
          O[((size_t)(b * NHEAD + h) * SEQ + nn) * HD + d] =
              f2bf((acc[mi][ni][r] + bval) * scale);
        }
      }
    }
  }
}

// Output projection GEMM, 128x128x32, m97 2-barrier structure (control).
// A bf16 (AO) via global_load_lds; out f32.
__global__ __launch_bounds__(256)
void gemm_proj(const u16* __restrict__ A, const u16* __restrict__ W,
               const float* __restrict__ bias, float* __restrict__ Op)
{
  __shared__ u16 As[128 * 32];
  __shared__ u16 Bs[128 * 32];
  const int n0 = blockIdx.x * 128, m0 = blockIdx.y * 128;
  const int t = threadIdx.x, lane = t & 63, w = t >> 6;
  const int grp = lane >> 4, lr = lane & 15;
  const int wr = (w >> 1) * 64, wc = (w & 1) * 64;

  f32x4 acc[4][4];
#pragma unroll
  for (int i = 0; i < 4; ++i)
#pragma unroll
    for (int j = 0; j < 4; ++j) acc[i][j] = (f32x4){0.f, 0.f, 0.f, 0.f};

  const int sr = lane >> 2, sc = (lane & 3) * 8;
  const u16* ag = A + (size_t)(m0 + w * 32 + sr) * HID + sc;
  const u16* wg = W + (size_t)(n0 + w * 32 + sr) * HID + sc;
  u16* al = As + (w * 32) * 32;
  u16* bl = Bs + (w * 32) * 32;

  for (int k0 = 0; k0 < HID; k0 += 32) {
    GLOAD_LDS16(ag + k0, al);
    GLOAD_LDS16(ag + (size_t)16 * HID + k0, al + 16 * 32);
    GLOAD_LDS16(wg + k0, bl);
    GLOAD_LDS16(wg + (size_t)16 * HID + k0, bl + 16 * 32);
    __syncthreads();
    bf16x8 af[4], bf[4];
#pragma unroll
    for (int mi = 0; mi < 4; ++mi)
      af[mi] = *(const bf16x8*)&As[(wr + mi * 16 + lr) * 32 + grp * 8];
#pragma unroll
    for (int ni = 0; ni < 4; ++ni)
      bf[ni] = *(const bf16x8*)&Bs[(wc + ni * 16 + lr) * 32 + grp * 8];
    __builtin_amdgcn_s_setprio(1);
#pragma unroll
    for (int mi = 0; mi < 4; ++mi)
#pragma unroll
      for (int ni = 0; ni < 4; ++ni)
        acc[mi][ni] = __builtin_amdgcn_mfma_f32_16x16x32_bf16(
            af[mi], bf[ni], acc[mi][ni], 0, 0, 0);
    __builtin_amdgcn_s_setprio(0);
    __syncthreads();
  }

#pragma unroll
  for (int mi = 0; mi < 4; ++mi) {
#pragma unroll
    for (int ni = 0; ni < 4; ++ni) {
      const int n = n0 + wc + ni * 16 + lr;
      const float bval = bias[n];
      const int mb = m0 + wr + mi * 16 + grp * 4;
#pragma unroll
      for (int r = 0; r < 4; ++r)
        Op[(size_t)(mb + r) * HID + n] = acc[mi][ni][r] + bval;
    }
  }
}

// Causal flash attention, PAIRED q-tiles (qtA, qtB=15-qtA) of one bh (R7
// structure, measured 67.6us). 2-buffer LDS, one raw barrier per tile.
// QBLK=128 (8 waves x 16 q/stream), KVBLK=64. Q pre-scaled by 0.125*log2(e).
// Q,K: [bh][n][64]; Vt: [bh][64][n]; bf16. O: [b][n][HID] bf16.
// chunk ^= (row&7) XOR swizzle via pre-swizzled global source (rule 21).
__global__ __launch_bounds__(512)
void attn_fwd(const u16* __restrict__ Q, const u16* __restrict__ K,
              const u16* __restrict__ Vt, u16* __restrict__ O)
{
  __shared__ u16 KB[2][4096];   // [buf][64 kv][64 d], 8 KB each
  __shared__ u16 VB[2][4096];   // [buf][64 d][64 kv], 8 KB each
  const int bh = blockIdx.y;
  const int t = threadIdx.x;
  const int w = t >> 6, lane = t & 63;
  const int grp = lane >> 4, lr = lane & 15;
  const int qtA = blockIdx.x;          // 0..7  (light tile)
  const int qtB = 15 - qtA;            // 8..15 (heavy tile)
  const int q0A = qtA * 128 + w * 16;
  const int q0B = qtB * 128 + w * 16;
  const int ntB = 2 * qtB + 2;         // staged kv tiles (covers A too)
  const size_t base = (size_t)bh * SEQ * HD;
  const float NEGINF = -__builtin_inff();

  const int srow = lane >> 3;
  const int scol = (lane & 7) ^ srow;
  const u16* kg = K + base + (size_t)(w * 8 + srow) * HD + scol * 8;
  const u16* vg = Vt + base + (size_t)(w * 8 + srow) * SEQ + scol * 8;

  const bf16x8 aqA0 = *(const bf16x8*)&Q[base + (size_t)(q0A + lr) * HD + grp * 8];
  const bf16x8 aqA1 = *(const bf16x8*)&Q[base + (size_t)(q0A + lr) * HD + grp * 8 + 32];
  const bf16x8 aqB0 = *(const bf16x8*)&Q[base + (size_t)(q0B + lr) * HD + grp * 8];
  const bf16x8 aqB1 = *(const bf16x8*)&Q[base + (size_t)(q0B + lr) * HD + grp * 8 + 32];

  float mA = NEGINF, lA = 0.f, mB = NEGINF, lB = 0.f;
  f32x4 oA[4], oB[4];
#pragma unroll
  for (int c = 0; c < 4; ++c) {
    oA[c] = (f32x4){0.f, 0.f, 0.f, 0.f};
    oB[c] = (f32x4){0.f, 0.f, 0.f, 0.f};
  }

  const int idqA = q0A >> 6;
  const int idqB = q0B >> 6;
  const int sw = lr & 7;

#define STAGE(bi, j0)                                              \
  {                                                                \
    GLOAD_LDS16(kg + (size_t)(j0) * HD, &KB[bi][w * 512]);         \
    GLOAD_LDS16(vg + (j0), &VB[bi][w * 512]);                      \
  }

#define COMPUTE(Q0, AQ0, AQ1, OACC, MI, LI, IDQ)                              \
  do {                                                                        \
    f32x4 sv[4];                                                              \
    __builtin_amdgcn_s_setprio(1);                                            \
    _Pragma("unroll")                                                         \
    for (int st = 0; st < 4; ++st) {                                          \
      const int ro = (st * 16 + lr) * 64;                                     \
      bf16x8 k0 = *(const bf16x8*)&KB[bi][ro + ((grp ^ sw) * 8)];             \
      bf16x8 k1 = *(const bf16x8*)&KB[bi][ro + (((grp + 4) ^ sw) * 8)];       \
      f32x4 s = (f32x4){0.f, 0.f, 0.f, 0.f};                                  \
      s = __builtin_amdgcn_mfma_f32_16x16x32_bf16(k0, (AQ0), s, 0, 0, 0);     \
      s = __builtin_amdgcn_mfma_f32_16x16x32_bf16(k1, (AQ1), s, 0, 0, 0);     \
      sv[st] = s;                                                             \
    }                                                                         \
    __builtin_amdgcn_s_setprio(0);                                            \
    bf16x4 bv[4][4];                                                          \
    _Pragma("unroll")                                                         \
    for (int st = 0; st < 4; ++st)                                            \
      _Pragma("unroll")                                                       \
      for (int c = 0; c < 4; ++c)                                             \
        bv[st][c] = *(const bf16x4*)&VB[bi][(c * 16 + lr) * 64 +              \
                        (((st * 2 + (grp >> 1)) ^ sw) * 8) + (grp & 1) * 4];  \
    if (it == (IDQ)) {                                                        \
      const int j0 = it << 6, qg = (Q0) + lr;                                 \
      _Pragma("unroll")                                                       \
      for (int st = 0; st < 4; ++st)                                          \
        _Pragma("unroll")                                                     \
        for (int r = 0; r < 4; ++r)                                           \
          if (j0 + st * 16 + grp * 4 + r > qg) sv[st][r] = NEGINF;            \
    }                                                                         \
    float tm = NEGINF;                                                        \
    _Pragma("unroll")                                                         \
    for (int st = 0; st < 4; ++st)                                            \
      tm = fmaxf(tm, fmaxf(fmaxf(sv[st][0], sv[st][1]),                       \
                           fmaxf(sv[st][2], sv[st][3])));                     \
    tm = fmaxf(tm, __shfl_xor(tm, 16));                                       \
    tm = fmaxf(tm, __shfl_xor(tm, 32));                                       \
    if (!__all(tm <= (MI) + 8.f)) {                                           \
      const float m_new = fmaxf((MI), tm);                                    \
      const float alpha = exp2f((MI)-m_new);                                  \
      (LI) *= alpha;                                                          \
      float af4[4];                                                           \
      _Pragma("unroll")                                                       \
      for (int r = 0; r < 4; ++r)                                             \
        af4[r] = __shfl(alpha, (lane & 48) + grp * 4 + r);                    \
      _Pragma("unroll")                                                       \
      for (int c = 0; c < 4; ++c)                                             \
        _Pragma("unroll")                                                     \
        for (int r = 0; r < 4; ++r) (OACC)[c][r] *= af4[r];                   \
      (MI) = m_new;                                                           \
    }                                                                         \
    float rs = 0.f;                                                           \
    _Pragma("unroll")                                                         \
    for (int st = 0; st < 4; ++st)                                            \
      _Pragma("unroll")                                                       \
      for (int r = 0; r < 4; ++r) {                                           \
        sv[st][r] = exp2f(sv[st][r] - (MI));                                  \
        rs += sv[st][r];                                                      \
      }                                                                       \
    rs += __shfl_xor(rs, 16);                                                 \
    rs += __shfl_xor(rs, 32);                                                 \
    (LI) += rs;                                                               \
    bf16x4 pa[4];                                                             \
    _Pragma("unroll")                                                         \
    for (int st = 0; st < 4; ++st)                                            \
      _Pragma("unroll")                                                       \
      for (int r = 0; r < 4; ++r) pa[st][r] = (short)f2bf_trunc(sv[st][r]);   \
    __builtin_amdgcn_s_setprio(1);                                            \
    _Pragma("unroll")                                                         \
    for (int st = 0; st < 4; ++st)                                            \
      _Pragma("unroll")                                                       \
      for (int c = 0; c < 4; ++c)                                             \
        (OACC)[c] = __builtin_amdgcn_mfma_f32_16x16x16bf16_1k(                \
            pa[st], bv[st][c], (OACC)[c], 0, 0, 0);                           \
    __builtin_amdgcn_s_setprio(0);                                            \
  } while (0)

  STAGE(0, 0);

  for (int it = 0; it < ntB; ++it) {
    const int bi = it & 1;
    asm volatile("s_waitcnt vmcnt(0)" ::: "memory");
    __builtin_amdgcn_s_barrier();
    __builtin_amdgcn_sched_barrier(0);
    asm volatile("" ::: "memory");
    if (it + 1 < ntB) STAGE(bi ^ 1, (it + 1) << 6);

    if (it <= idqB) COMPUTE(q0B, aqB0, aqB1, oB, mB, lB, idqB);
    if (it <= idqA) COMPUTE(q0A, aqA0, aqA1, oA, mA, lA, idqA);
  }
#undef STAGE
#undef COMPUTE

  const int b = bh >> 4, h = bh & (NHEAD - 1);
#pragma unroll
  for (int r = 0; r < 4; ++r) {
    const float liB = __shfl(lB, (lane & 48) + grp * 4 + r);
    const float invB = 1.f / liB;
    const int nB = q0B + grp * 4 + r;
#pragma unroll
    for (int c = 0; c < 4; ++c)
      O[(size_t)(b * SEQ + nB) * HID + h * HD + c * 16 + lr] =
          f2bf(oB[c][r] * invB);
    const float liA = __shfl(lA, (lane & 48) + grp * 4 + r);
    const float invA = 1.f / liA;
    const int nA = q0A + grp * 4 + r;
#pragma unroll
    for (int c = 0; c < 4; ++c)
      O[(size_t)(b * SEQ + nA) * HID + h * HD + c * 16 + lr] =
          f2bf(oA[c][r] * invA);
  }
}

extern "C" void kernel_launch(void* const* d_in, const int* in_sizes, int n_in,
                              void* d_out, int out_size, void* d_ws, size_t ws_size,
                              hipStream_t stream) {
  const float* q  = (const float*)d_in[0];
  const float* k  = (const float*)d_in[1];
  const float* v  = (const float*)d_in[2];
  /* d_in[3] = mask: tril by construction -> causal handled structurally */
  const float* Wq = (const float*)d_in[4];
  const float* bq = (const float*)d_in[5];
  const float* Wk = (const float*)d_in[6];
  const float* bk = (const float*)d_in[7];
  const float* Wv = (const float*)d_in[8];
  const float* bv = (const float*)d_in[9];
  const float* Wp = (const float*)d_in[10];
  const float* bp = (const float*)d_in[11];
  float* out = (float*)d_out;

  // ws layout (40 MiB): AO | Wcat(3 weights) | Wpb | Qh | Kh | Vt
  char* ws = (char*)d_ws;
  u16* AO   = (u16*)(ws);                  // 8 MiB
  u16* Wcat = (u16*)(ws + ( 8u << 20));    // 6 MiB
  u16* Wpb  = (u16*)(ws + (14u << 20));    // 2 MiB
  u16* Qh   = (u16*)(ws + (16u << 20));    // 8 MiB
  u16* Kh   = (u16*)(ws + (24u << 20));    // 8 MiB
  u16* Vt   = (u16*)(ws + (32u << 20));    // 8 MiB

  const float qscale = 0.125f * 1.4426950408889634f;  // 1/sqrt(64) * log2(e)

  conv_w<<<2048, 256, 0, stream>>>(Wq, Wk, Wv, Wp, Wcat, Wpb);
  gemm_qkv<<<dim3(24, 32), 256, 0, stream>>>(
      q, k, v, Wcat, bq, bk, bv, Qh, Kh, Vt, qscale);
  attn_fwd<<<dim3(8, NB * NHEAD), 512, 0, stream>>>(Qh, Kh, Vt, AO);
  gemm_proj<<<dim3(8, 32), 256, 0, stream>>>(AO, Wpb, bp, out);
}

// Round 10
// 144.501 us; speedup vs baseline: 1.1584x; 1.1354x over previous
//
#include <hip/hip_runtime.h>

typedef unsigned short u16;
typedef __attribute__((ext_vector_type(8))) short bf16x8;
typedef __attribute__((ext_vector_type(4))) short bf16x4;
typedef __attribute__((ext_vector_type(4))) float f32x4;

#define NB 2
#define SEQ 2048
#define HID 1024
#define NHEAD 16
#define HD 64
#define MROWS (NB * SEQ) /* 4096 */

__device__ __forceinline__ u16 f2bf(float f) {
  union { float f; unsigned u; } x; x.f = f;
  unsigned r = x.u + 0x7fffu + ((x.u >> 16) & 1u);
  return (u16)(r >> 16);
}
__device__ __forceinline__ u16 f2bf_trunc(float f) {
  union { float f; unsigned u; } x; x.f = f;
  return (u16)(x.u >> 16);
}

#define GLOAD_LDS16(g, l)                                                   \
  __builtin_amdgcn_global_load_lds(                                         \
      (const __attribute__((address_space(1))) void*)(g),                   \
      (__attribute__((address_space(3))) void*)(l), 16, 0, 0)

// weights-only f32 -> bf16: Wq,Wk,Wv -> Wcat ; Wp -> Wpb  (524288 vec8)
__global__ __launch_bounds__(256)
void conv_w(const float* __restrict__ wq, const float* __restrict__ wk,
            const float* __restrict__ wv, const float* __restrict__ wp,
            u16* __restrict__ wcat, u16* __restrict__ wpb)
{
  const int i = blockIdx.x * 256 + threadIdx.x;  // < 524288
  const int seg = i >> 17;                        // /131072: 0=Wq 1=Wk 2=Wv 3=Wp
  const int off = i & 131071;
  const float* s = (seg == 0 ? wq : seg == 1 ? wk : seg == 2 ? wv : wp) +
                   (size_t)off * 8;
  u16* d = (seg < 3 ? wcat + (size_t)seg * 1048576 : wpb) + (size_t)off * 8;
  f32x4 a = *(const f32x4*)s;
  f32x4 b = *(const f32x4*)(s + 4);
  bf16x8 o;
#pragma unroll
  for (int j = 0; j < 4; ++j) { o[j] = (short)f2bf(a[j]); o[4 + j] = (short)f2bf(b[j]); }
  *(bf16x8*)d = o;
}

// Fused QKV projection GEMM, 128x128x32, f32 A converted in-register.
// XCD-PINNED GROUP SWIZZLE: physical bid p -> presumed XCD c = p&7.
// Group G (one (g, m0) A-row-block, 8 n-subtile members) is pinned to one
// XCD so its A rows are fetched into ONE L2 once (512 KB << 4 MiB L2),
// instead of 8 XCDs each fetching a copy (R9: 207 MB FETCH).
__global__ __launch_bounds__(256)
void gemm_qkv(const float* __restrict__ A0, const float* __restrict__ A1,
              const float* __restrict__ A2, const u16* __restrict__ Wcat,
              const float* __restrict__ b0, const float* __restrict__ b1,
              const float* __restrict__ b2,
              u16* __restrict__ Qh, u16* __restrict__ Kh, u16* __restrict__ Vt,
              float qscale)
{
  __shared__ u16 As[2][4096];   // [buf][128 rows][32 k] bf16, 8 KB each
  __shared__ u16 Bs[2][4096];
  // --- swizzle: p -> (G = c*12 + i%12, j = i/12); bijective [0,768) ---
  const int p = blockIdx.x;
  const int c = p & 7;                 // presumed XCD (round-robin dispatch)
  const int i_ = p >> 3;               // [0,96) position within XCD stream
  const int G = c * 12 + (i_ % 12);    // group: 8 members share A rows + XCD
  const int j = i_ / 12;               // member = n-subtile [0,8)
  const int g = G >> 5;                // tensor select 0..2 (q/k/v)
  const int n0 = (g * 8 + j) * 128;    // global n-tile
  const int m0 = (G & 31) * 128;       // m-tile
  const float* A = (g == 0) ? A0 : (g == 1) ? A1 : A2;
  const float* bias = (g == 0) ? b0 : (g == 1) ? b1 : b2;
  const int t = threadIdx.x, lane = t & 63, w = t >> 6;
  const int grp = lane >> 4, lr = lane & 15;
  const int wr = (w >> 1) * 64, wc = (w & 1) * 64;

  f32x4 acc[4][4];
#pragma unroll
  for (int i = 0; i < 4; ++i)
#pragma unroll
    for (int j2 = 0; j2 < 4; ++j2) acc[i][j2] = (f32x4){0.f, 0.f, 0.f, 0.f};

  // W staging (gload_lds): wave w rows [w*32, +32), lane scatter 16B linear
  const int sr = lane >> 2, sc = (lane & 3) * 8;
  const u16* wg = Wcat + (size_t)(n0 + w * 32 + sr) * HID + sc;
  // A staging (f32 regs): row w*32 + lane/2, col half (lane&1)*16  (64B/lane)
  const int arow = w * 32 + (lane >> 1);
  const float* ag = A + (size_t)(m0 + arow) * HID + (lane & 1) * 16;
  const int lbase = arow * 32 + (lane & 1) * 16;  // LDS elem offset (linear)

  f32x4 a4[4];
#define ALOAD(K0)                                                   \
  { const float* p_ = ag + (K0);                                    \
    a4[0] = *(const f32x4*)p_;       a4[1] = *(const f32x4*)(p_ + 4); \
    a4[2] = *(const f32x4*)(p_ + 8); a4[3] = *(const f32x4*)(p_ + 12); }
#define ACONV(BI)                                                   \
  { bf16x8 o0, o1;                                                  \
    _Pragma("unroll")                                               \
    for (int jj = 0; jj < 4; ++jj) {                                \
      o0[jj] = (short)f2bf(a4[0][jj]); o0[4 + jj] = (short)f2bf(a4[1][jj]); \
      o1[jj] = (short)f2bf(a4[2][jj]); o1[4 + jj] = (short)f2bf(a4[3][jj]); \
    }                                                               \
    *(bf16x8*)&As[BI][lbase] = o0; *(bf16x8*)&As[BI][lbase + 8] = o1; }
#define WSTAGE(BI, K0)                                              \
  { GLOAD_LDS16(wg + (K0), &Bs[BI][(w * 32) * 32]);                 \
    GLOAD_LDS16(wg + (size_t)16 * HID + (K0), &Bs[BI][(w * 32 + 16) * 32]); }

  // prologue: stage tile 0, issue A{1}
  ALOAD(0);
  asm volatile("s_waitcnt vmcnt(0)" ::: "memory");
  ACONV(0);
  WSTAGE(0, 0);
  ALOAD(32);
  asm volatile("s_waitcnt lgkmcnt(0)" ::: "memory");

  for (int it = 0; it < 32; ++it) {
    const int cur = it & 1;
    asm volatile("s_waitcnt vmcnt(4)" ::: "memory");  // W{it} landed; A{it+1} flies
    __builtin_amdgcn_s_barrier();
    __builtin_amdgcn_sched_barrier(0);
    WSTAGE(cur ^ 1, (it + 1 < 32) ? (it + 1) * 32 : 0);  // full phase to land
    bf16x8 af[4], bf[4];
#pragma unroll
    for (int mi = 0; mi < 4; ++mi)
      af[mi] = *(const bf16x8*)&As[cur][(wr + mi * 16 + lr) * 32 + grp * 8];
#pragma unroll
    for (int ni = 0; ni < 4; ++ni)
      bf[ni] = *(const bf16x8*)&Bs[cur][(wc + ni * 16 + lr) * 32 + grp * 8];
    __builtin_amdgcn_s_setprio(1);
#pragma unroll
    for (int mi = 0; mi < 4; ++mi)
#pragma unroll
      for (int ni = 0; ni < 4; ++ni)
        acc[mi][ni] = __builtin_amdgcn_mfma_f32_16x16x32_bf16(
            af[mi], bf[ni], acc[mi][ni], 0, 0, 0);
    __builtin_amdgcn_s_setprio(0);
    asm volatile("s_waitcnt vmcnt(2)" ::: "memory");  // A{it+1} regs ready
    ACONV(cur ^ 1);
    ALOAD((it + 2 < 32) ? (it + 2) * 32 : 0);
    asm volatile("s_waitcnt lgkmcnt(0)" ::: "memory");  // ds_writes visible
  }
  asm volatile("s_waitcnt vmcnt(0) lgkmcnt(0)" ::: "memory");
#undef ALOAD
#undef ACONV
#undef WSTAGE

  const float scale = (g == 0) ? qscale : 1.f;
#pragma unroll
  for (int mi = 0; mi < 4; ++mi) {
#pragma unroll
    for (int ni = 0; ni < 4; ++ni) {
      const int nl = (n0 & (HID - 1)) + wc + ni * 16 + lr;
      const float bval = bias[nl];
      const int mb = m0 + wr + mi * 16 + grp * 4;
      const int h = nl >> 6, d = nl & (HD - 1);
      if (g == 2) {  // V transposed: vector over r (m-contiguous)
        const int b = mb >> 11, nn = mb & (SEQ - 1);
        bf16x4 pk;
#pragma unroll
        for (int r = 0; r < 4; ++r)
          pk[r] = (short)f2bf(acc[mi][ni][r] + bval);
        *(bf16x4*)&Vt[((size_t)(b * NHEAD + h) * HD + d) * SEQ + nn] = pk;
      } else {
        u16* O = (g == 0) ? Qh : Kh;
#pragma unroll
        for (int r = 0; r < 4; ++r) {
          const int m = mb + r;
          const int b = m >> 11, nn = m & (SEQ - 1);
          O[((size_t)(b * NHEAD + h) * SEQ + nn) * HD + d] =
              f2bf((acc[mi][ni][r] + bval) * scale);
        }
      }
    }
  }
}

// Output projection GEMM, 128x128x32, m97 2-barrier structure (control).
// A bf16 (AO) via global_load_lds; out f32.
__global__ __launch_bounds__(256)
void gemm_proj(const u16* __restrict__ A, const u16* __restrict__ W,
               const float* __restrict__ bias, float* __restrict__ Op)
{
  __shared__ u16 As[128 * 32];
  __shared__ u16 Bs[128 * 32];
  const int n0 = blockIdx.x * 128, m0 = blockIdx.y * 128;
  const int t = threadIdx.x, lane = t & 63, w = t >> 6;
  const int grp = lane >> 4, lr = lane & 15;
  const int wr = (w >> 1) * 64, wc = (w & 1) * 64;

  f32x4 acc[4][4];
#pragma unroll
  for (int i = 0; i < 4; ++i)
#pragma unroll
    for (int j = 0; j < 4; ++j) acc[i][j] = (f32x4){0.f, 0.f, 0.f, 0.f};

  const int sr = lane >> 2, sc = (lane & 3) * 8;
  const u16* ag = A + (size_t)(m0 + w * 32 + sr) * HID + sc;
  const u16* wg = W + (size_t)(n0 + w * 32 + sr) * HID + sc;
  u16* al = As + (w * 32) * 32;
  u16* bl = Bs + (w * 32) * 32;

  for (int k0 = 0; k0 < HID; k0 += 32) {
    GLOAD_LDS16(ag + k0, al);
    GLOAD_LDS16(ag + (size_t)16 * HID + k0, al + 16 * 32);
    GLOAD_LDS16(wg + k0, bl);
    GLOAD_LDS16(wg + (size_t)16 * HID + k0, bl + 16 * 32);
    __syncthreads();
    bf16x8 af[4], bf[4];
#pragma unroll
    for (int mi = 0; mi < 4; ++mi)
      af[mi] = *(const bf16x8*)&As[(wr + mi * 16 + lr) * 32 + grp * 8];
#pragma unroll
    for (int ni = 0; ni < 4; ++ni)
      bf[ni] = *(const bf16x8*)&Bs[(wc + ni * 16 + lr) * 32 + grp * 8];
    __builtin_amdgcn_s_setprio(1);
#pragma unroll
    for (int mi = 0; mi < 4; ++mi)
#pragma unroll
      for (int ni = 0; ni < 4; ++ni)
        acc[mi][ni] = __builtin_amdgcn_mfma_f32_16x16x32_bf16(
            af[mi], bf[ni], acc[mi][ni], 0, 0, 0);
    __builtin_amdgcn_s_setprio(0);
    __syncthreads();
  }

#pragma unroll
  for (int mi = 0; mi < 4; ++mi) {
#pragma unroll
    for (int ni = 0; ni < 4; ++ni) {
      const int n = n0 + wc + ni * 16 + lr;
      const float bval = bias[n];
      const int mb = m0 + wr + mi * 16 + grp * 4;
#pragma unroll
      for (int r = 0; r < 4; ++r)
        Op[(size_t)(mb + r) * HID + n] = acc[mi][ni][r] + bval;
    }
  }
}

// Causal flash attention, PAIRED q-tiles (qtA, qtB=15-qtA) of one bh (R7
// structure, measured 67.6us). 2-buffer LDS, one raw barrier per tile.
// QBLK=128 (8 waves x 16 q/stream), KVBLK=64. Q pre-scaled by 0.125*log2(e).
// Q,K: [bh][n][64]; Vt: [bh][64][n]; bf16. O: [b][n][HID] bf16.
// chunk ^= (row&7) XOR swizzle via pre-swizzled global source (rule 21).
__global__ __launch_bounds__(512)
void attn_fwd(const u16* __restrict__ Q, const u16* __restrict__ K,
              const u16* __restrict__ Vt, u16* __restrict__ O)
{
  __shared__ u16 KB[2][4096];   // [buf][64 kv][64 d], 8 KB each
  __shared__ u16 VB[2][4096];   // [buf][64 d][64 kv], 8 KB each
  const int bh = blockIdx.y;
  const int t = threadIdx.x;
  const int w = t >> 6, lane = t & 63;
  const int grp = lane >> 4, lr = lane & 15;
  const int qtA = blockIdx.x;          // 0..7  (light tile)
  const int qtB = 15 - qtA;            // 8..15 (heavy tile)
  const int q0A = qtA * 128 + w * 16;
  const int q0B = qtB * 128 + w * 16;
  const int ntB = 2 * qtB + 2;         // staged kv tiles (covers A too)
  const size_t base = (size_t)bh * SEQ * HD;
  const float NEGINF = -__builtin_inff();

  const int srow = lane >> 3;
  const int scol = (lane & 7) ^ srow;
  const u16* kg = K + base + (size_t)(w * 8 + srow) * HD + scol * 8;
  const u16* vg = Vt + base + (size_t)(w * 8 + srow) * SEQ + scol * 8;

  const bf16x8 aqA0 = *(const bf16x8*)&Q[base + (size_t)(q0A + lr) * HD + grp * 8];
  const bf16x8 aqA1 = *(const bf16x8*)&Q[base + (size_t)(q0A + lr) * HD + grp * 8 + 32];
  const bf16x8 aqB0 = *(const bf16x8*)&Q[base + (size_t)(q0B + lr) * HD + grp * 8];
  const bf16x8 aqB1 = *(const bf16x8*)&Q[base + (size_t)(q0B + lr) * HD + grp * 8 + 32];

  float mA = NEGINF, lA = 0.f, mB = NEGINF, lB = 0.f;
  f32x4 oA[4], oB[4];
#pragma unroll
  for (int c = 0; c < 4; ++c) {
    oA[c] = (f32x4){0.f, 0.f, 0.f, 0.f};
    oB[c] = (f32x4){0.f, 0.f, 0.f, 0.f};
  }

  const int idqA = q0A >> 6;
  const int idqB = q0B >> 6;
  const int sw = lr & 7;

#define STAGE(bi, j0)                                              \
  {                                                                \
    GLOAD_LDS16(kg + (size_t)(j0) * HD, &KB[bi][w * 512]);         \
    GLOAD_LDS16(vg + (j0), &VB[bi][w * 512]);                      \
  }

#define COMPUTE(Q0, AQ0, AQ1, OACC, MI, LI, IDQ)                              \
  do {                                                                        \
    f32x4 sv[4];                                                              \
    __builtin_amdgcn_s_setprio(1);                                            \
    _Pragma("unroll")                                                         \
    for (int st = 0; st < 4; ++st) {                                          \
      const int ro = (st * 16 + lr) * 64;                                     \
      bf16x8 k0 = *(const bf16x8*)&KB[bi][ro + ((grp ^ sw) * 8)];             \
      bf16x8 k1 = *(const bf16x8*)&KB[bi][ro + (((grp + 4) ^ sw) * 8)];       \
      f32x4 s = (f32x4){0.f, 0.f, 0.f, 0.f};                                  \
      s = __builtin_amdgcn_mfma_f32_16x16x32_bf16(k0, (AQ0), s, 0, 0, 0);     \
      s = __builtin_amdgcn_mfma_f32_16x16x32_bf16(k1, (AQ1), s, 0, 0, 0);     \
      sv[st] = s;                                                             \
    }                                                                         \
    __builtin_amdgcn_s_setprio(0);                                            \
    bf16x4 bv[4][4];                                                          \
    _Pragma("unroll")                                                         \
    for (int st = 0; st < 4; ++st)                                            \
      _Pragma("unroll")                                                       \
      for (int c = 0; c < 4; ++c)                                             \
        bv[st][c] = *(const bf16x4*)&VB[bi][(c * 16 + lr) * 64 +              \
                        (((st * 2 + (grp >> 1)) ^ sw) * 8) + (grp & 1) * 4];  \
    if (it == (IDQ)) {                                                        \
      const int j0 = it << 6, qg = (Q0) + lr;                                 \
      _Pragma("unroll")                                                       \
      for (int st = 0; st < 4; ++st)                                          \
        _Pragma("unroll")                                                     \
        for (int r = 0; r < 4; ++r)                                           \
          if (j0 + st * 16 + grp * 4 + r > qg) sv[st][r] = NEGINF;            \
    }                                                                         \
    float tm = NEGINF;                                                        \
    _Pragma("unroll")                                                         \
    for (int st = 0; st < 4; ++st)                                            \
      tm = fmaxf(tm, fmaxf(fmaxf(sv[st][0], sv[st][1]),                       \
                           fmaxf(sv[st][2], sv[st][3])));                     \
    tm = fmaxf(tm, __shfl_xor(tm, 16));                                       \
    tm = fmaxf(tm, __shfl_xor(tm, 32));                                       \
    if (!__all(tm <= (MI) + 8.f)) {                                           \
      const float m_new = fmaxf((MI), tm);                                    \
      const float alpha = exp2f((MI)-m_new);                                  \
      (LI) *= alpha;                                                          \
      float af4[4];                                                           \
      _Pragma("unroll")                                                       \
      for (int r = 0; r < 4; ++r)                                             \
        af4[r] = __shfl(alpha, (lane & 48) + grp * 4 + r);                    \
      _Pragma("unroll")                                                       \
      for (int c = 0; c < 4; ++c)                                             \
        _Pragma("unroll")                                                     \
        for (int r = 0; r < 4; ++r) (OACC)[c][r] *= af4[r];                   \
      (MI) = m_new;                                                           \
    }                                                                         \
    float rs = 0.f;                                                           \
    _Pragma("unroll")                                                         \
    for (int st = 0; st < 4; ++st)                                            \
      _Pragma("unroll")                                                       \
      for (int r = 0; r < 4; ++r) {                                           \
        sv[st][r] = exp2f(sv[st][r] - (MI));                                  \
        rs += sv[st][r];                                                      \
      }                                                                       \
    rs += __shfl_xor(rs, 16);                                                 \
    rs += __shfl_xor(rs, 32);                                                 \
    (LI) += rs;                                                               \
    bf16x4 pa[4];                                                             \
    _Pragma("unroll")                                                         \
    for (int st = 0; st < 4; ++st)                                            \
      _Pragma("unroll")                                                       \
      for (int r = 0; r < 4; ++r) pa[st][r] = (short)f2bf_trunc(sv[st][r]);   \
    __builtin_amdgcn_s_setprio(1);                                            \
    _Pragma("unroll")                                                         \
    for (int st = 0; st < 4; ++st)                                            \
      _Pragma("unroll")                                                       \
      for (int c = 0; c < 4; ++c)                                             \
        (OACC)[c] = __builtin_amdgcn_mfma_f32_16x16x16bf16_1k(                \
            pa[st], bv[st][c], (OACC)[c], 0, 0, 0);                           \
    __builtin_amdgcn_s_setprio(0);                                            \
  } while (0)

  STAGE(0, 0);

  for (int it = 0; it < ntB; ++it) {
    const int bi = it & 1;
    asm volatile("s_waitcnt vmcnt(0)" ::: "memory");
    __builtin_amdgcn_s_barrier();
    __builtin_amdgcn_sched_barrier(0);
    asm volatile("" ::: "memory");
    if (it + 1 < ntB) STAGE(bi ^ 1, (it + 1) << 6);

    if (it <= idqB) COMPUTE(q0B, aqB0, aqB1, oB, mB, lB, idqB);
    if (it <= idqA) COMPUTE(q0A, aqA0, aqA1, oA, mA, lA, idqA);
  }
#undef STAGE
#undef COMPUTE

  const int b = bh >> 4, h = bh & (NHEAD - 1);
#pragma unroll
  for (int r = 0; r < 4; ++r) {
    const float liB = __shfl(lB, (lane & 48) + grp * 4 + r);
    const float invB = 1.f / liB;
    const int nB = q0B + grp * 4 + r;
#pragma unroll
    for (int c = 0; c < 4; ++c)
      O[(size_t)(b * SEQ + nB) * HID + h * HD + c * 16 + lr] =
          f2bf(oB[c][r] * invB);
    const float liA = __shfl(lA, (lane & 48) + grp * 4 + r);
    const float invA = 1.f / liA;
    const int nA = q0A + grp * 4 + r;
#pragma unroll
    for (int c = 0; c < 4; ++c)
      O[(size_t)(b * SEQ + nA) * HID + h * HD + c * 16 + lr] =
          f2bf(oA[c][r] * invA);
  }
}

extern "C" void kernel_launch(void* const* d_in, const int* in_sizes, int n_in,
                              void* d_out, int out_size, void* d_ws, size_t ws_size,
                              hipStream_t stream) {
  const float* q  = (const float*)d_in[0];
  const float* k  = (const float*)d_in[1];
  const float* v  = (const float*)d_in[2];
  /* d_in[3] = mask: tril by construction -> causal handled structurally */
  const float* Wq = (const float*)d_in[4];
  const float* bq = (const float*)d_in[5];
  const float* Wk = (const float*)d_in[6];
  const float* bk = (const float*)d_in[7];
  const float* Wv = (const float*)d_in[8];
  const float* bv = (const float*)d_in[9];
  const float* Wp = (const float*)d_in[10];
  const float* bp = (const float*)d_in[11];
  float* out = (float*)d_out;

  // ws layout (40 MiB): AO | Wcat(3 weights) | Wpb | Qh | Kh | Vt
  char* ws = (char*)d_ws;
  u16* AO   = (u16*)(ws);                  // 8 MiB
  u16* Wcat = (u16*)(ws + ( 8u << 20));    // 6 MiB
  u16* Wpb  = (u16*)(ws + (14u << 20));    // 2 MiB
  u16* Qh   = (u16*)(ws + (16u << 20));    // 8 MiB
  u16* Kh   = (u16*)(ws + (24u << 20));    // 8 MiB
  u16* Vt   = (u16*)(ws + (32u << 20));    // 8 MiB

  const float qscale = 0.125f * 1.4426950408889634f;  // 1/sqrt(64) * log2(e)

  conv_w<<<2048, 256, 0, stream>>>(Wq, Wk, Wv, Wp, Wcat, Wpb);
  gemm_qkv<<<768, 256, 0, stream>>>(
      q, k, v, Wcat, bq, bk, bv, Qh, Kh, Vt, qscale);
  attn_fwd<<<dim3(8, NB * NHEAD), 512, 0, stream>>>(Qh, Kh, Vt, AO);
  gemm_proj<<<dim3(8, 32), 256, 0, stream>>>(AO, Wpb, bp, out);
}